// Round 1
// baseline (838.461 us; speedup 1.0000x reference)
//
#include <hip/hip_runtime.h>
#include <stdint.h>

// Problem constants (reference: N=8192, D=256, BATCH=64; thr read from input)
#define NPTS 8192
#define DIM  256
#define CAP  32768      // edge capacity in workspace (expected ~1100 edges)
#define SORT_CAP 8192   // sorted-edge LDS capacity

// ---------------------------------------------------------------------------
// Kernel 0: zero the edge counter (d_ws is poisoned 0xAA before every launch)
// ---------------------------------------------------------------------------
__global__ void init_count(unsigned* ec) {
    if (threadIdx.x == 0) *ec = 0u;
}

// ---------------------------------------------------------------------------
// Kernel 1: upper-triangle Gram matrix, threshold, emit edges (i<<13)|j.
// 64x64 tile per 256-thread block, 4x4 micro-tile per thread, fp32 FMA.
// LDS layout XOR-swizzled so ds_read_b128 along k is bank-conflict-free.
// ---------------------------------------------------------------------------
__global__ __launch_bounds__(256) void edge_kernel(
        const float* __restrict__ V,
        const float* __restrict__ thr_p,
        unsigned*    __restrict__ ec,
        unsigned*    __restrict__ edges) {
    const int bi = blockIdx.y;   // i-tile
    const int bj = blockIdx.x;   // j-tile
    if (bj < bi) return;         // upper triangle of tiles only

    __shared__ float As[64 * 64];
    __shared__ float Bs[64 * 64];

    const float thr = thr_p[0];
    const int tid = threadIdx.x;
    const int tx = tid & 15;          // j micro index
    const int ty = tid >> 4;          // i micro index
    const int i0 = bi * 64, j0 = bj * 64;

    float acc[4][4];
#pragma unroll
    for (int r = 0; r < 4; ++r)
#pragma unroll
        for (int c = 0; c < 4; ++c) acc[r][c] = 0.f;

    for (int kc = 0; kc < DIM; kc += 64) {
        // ---- stage 64x64 fp32 tiles (swizzled) ----
#pragma unroll
        for (int s4 = 0; s4 < 4; ++s4) {
            int slot = tid + s4 * 256;            // 0..1023 float4 slots
            int r  = slot >> 4;
            int k4 = slot & 15;
            float4 va = *reinterpret_cast<const float4*>(
                &V[(size_t)(i0 + r) * DIM + kc + k4 * 4]);
            float4 vb = *reinterpret_cast<const float4*>(
                &V[(size_t)(j0 + r) * DIM + kc + k4 * 4]);
            int w = r * 64 + ((k4 ^ (r & 7)) << 2);   // XOR swizzle, 16B aligned
            *reinterpret_cast<float4*>(&As[w]) = va;
            *reinterpret_cast<float4*>(&Bs[w]) = vb;
        }
        __syncthreads();

        // ---- compute: 16 k4-steps of 4 k each ----
#pragma unroll
        for (int k4 = 0; k4 < 16; ++k4) {
            float4 a[4], b[4];
#pragma unroll
            for (int r = 0; r < 4; ++r) {
                int row = ty * 4 + r;
                a[r] = *reinterpret_cast<const float4*>(
                    &As[row * 64 + ((k4 ^ (row & 7)) << 2)]);
            }
#pragma unroll
            for (int c = 0; c < 4; ++c) {
                int row = tx * 4 + c;
                b[c] = *reinterpret_cast<const float4*>(
                    &Bs[row * 64 + ((k4 ^ (row & 7)) << 2)]);
            }
#pragma unroll
            for (int r = 0; r < 4; ++r)
#pragma unroll
                for (int c = 0; c < 4; ++c) {
                    acc[r][c] = fmaf(a[r].x, b[c].x, acc[r][c]);
                    acc[r][c] = fmaf(a[r].y, b[c].y, acc[r][c]);
                    acc[r][c] = fmaf(a[r].z, b[c].z, acc[r][c]);
                    acc[r][c] = fmaf(a[r].w, b[c].w, acc[r][c]);
                }
        }
        __syncthreads();
    }

    // ---- emit edges (strict upper triangle) ----
#pragma unroll
    for (int r = 0; r < 4; ++r)
#pragma unroll
        for (int c = 0; c < 4; ++c) {
            int i = i0 + ty * 4 + r;
            int j = j0 + tx * 4 + c;
            if (j > i && acc[r][c] >= thr) {
                unsigned p = atomicAdd(ec, 1u);
                if (p < CAP) edges[p] = ((unsigned)i << 13) | (unsigned)j;
            }
        }
}

// ---------------------------------------------------------------------------
// Kernel 2: one block. Counting-sort edges by row i (LDS), then serial
// union-find in LDS replicating the reference's sequential merge order,
// then parallel root write-out.
// Exact-order guarantee: rows ascending; within a row, union direction is
// always parent[find(j)] = find(i), and find(i) is invariant within a row,
// so j-order inside a row does not matter.
// ---------------------------------------------------------------------------
__global__ __launch_bounds__(1024) void uf_kernel(
        const unsigned* __restrict__ ec,
        const unsigned* __restrict__ edges,
        int* __restrict__ out) {
    __shared__ unsigned cnt[NPTS];        // 32 KB: counts -> offsets
    __shared__ unsigned sedge[SORT_CAP];  // 32 KB: row-sorted edges
    __shared__ int      par[NPTS];        // 32 KB: union-find parents
    __shared__ int      wexc[17];

    const int tid  = threadIdx.x;
    const int lane = tid & 63;
    const int wid  = tid >> 6;

    unsigned EC = *ec;
    if (EC > CAP) EC = CAP;

    for (int t = tid; t < NPTS; t += 1024) { cnt[t] = 0u; par[t] = t; }
    __syncthreads();

    // histogram rows
    for (unsigned e = tid; e < EC; e += 1024)
        atomicAdd(&cnt[edges[e] >> 13], 1u);
    __syncthreads();

    // exclusive scan over 8192 counts (8 per thread, wave scan, block combine)
    unsigned v[8], s = 0;
    const unsigned base = (unsigned)tid * 8u;
#pragma unroll
    for (int q = 0; q < 8; ++q) { v[q] = cnt[base + q]; s += v[q]; }
    int inc = (int)s;
#pragma unroll
    for (int d = 1; d < 64; d <<= 1) {
        int u = __shfl_up(inc, d);
        if (lane >= d) inc += u;
    }
    if (lane == 63) wexc[wid + 1] = inc;
    if (tid == 0)   wexc[0] = 0;
    __syncthreads();
    if (tid == 0) {
        for (int w = 1; w <= 16; ++w) wexc[w] += wexc[w - 1];
    }
    __syncthreads();
    unsigned o = (unsigned)(wexc[wid] + inc - (int)s);
#pragma unroll
    for (int q = 0; q < 8; ++q) { cnt[base + q] = o; o += v[q]; }
    __syncthreads();

    // scatter into row-sorted order
    for (unsigned e = tid; e < EC; e += 1024) {
        unsigned key = edges[e];
        unsigned p = atomicAdd(&cnt[key >> 13], 1u);
        if (p < SORT_CAP) sedge[p] = key;
    }
    __syncthreads();

    // serial union-find, edges in ascending-row order
    unsigned SC = EC > SORT_CAP ? SORT_CAP : EC;
    if (tid == 0) {
        for (unsigned e = 0; e < SC; ++e) {
            unsigned key = sedge[e];
            int i = (int)(key >> 13);
            int j = (int)(key & 8191u);
            // dual-chain walk: overlap the two dependent LDS latency chains
            int ri = i, rj = j;
            int pi = par[ri], pj = par[rj];
            while (pi != ri || pj != rj) {
                ri = pi; rj = pj;
                pi = par[ri]; pj = par[rj];
            }
            if (rj != ri) par[rj] = ri;   // directed union into i's root
            par[i] = ri;                  // path compression (root-preserving)
            par[j] = ri;
        }
    }
    __syncthreads();

    // parallel root write-out (read-only finds)
    for (int t = tid; t < NPTS; t += 1024) {
        int r = t;
        while (par[r] != r) r = par[r];
        out[t] = r;
    }
}

extern "C" void kernel_launch(void* const* d_in, const int* in_sizes, int n_in,
                              void* d_out, int out_size, void* d_ws, size_t ws_size,
                              hipStream_t stream) {
    const float* V     = (const float*)d_in[0];
    const float* thr_p = (const float*)d_in[1];
    // d_in[2] (batch_size) provably does not affect the result (see analysis).

    unsigned* ec    = (unsigned*)d_ws;
    unsigned* edges = (unsigned*)((char*)d_ws + 64);
    int*      out   = (int*)d_out;

    hipLaunchKernelGGL(init_count, dim3(1), dim3(64), 0, stream, ec);
    hipLaunchKernelGGL(edge_kernel, dim3(128, 128), dim3(256), 0, stream,
                       V, thr_p, ec, edges);
    hipLaunchKernelGGL(uf_kernel, dim3(1), dim3(1024), 0, stream,
                       ec, edges, out);
}

// Round 2
// 446.616 us; speedup vs baseline: 1.8774x; 1.8774x over previous
//
#include <hip/hip_runtime.h>
#include <stdint.h>

// Problem constants (reference: N=8192, D=256, BATCH=64; thr read from input)
#define NPTS 8192
#define DIM  256
#define CAP  32768      // edge capacity in workspace (expected ~1100 edges)
#define SORT_CAP 8192   // sorted-edge LDS capacity

// ---------------------------------------------------------------------------
// Kernel 0: zero the edge counter (d_ws is poisoned 0xAA before every launch)
// ---------------------------------------------------------------------------
__global__ void init_count(unsigned* ec) {
    if (threadIdx.x == 0) *ec = 0u;
}

// ---------------------------------------------------------------------------
// Kernel 1: upper-triangle Gram matrix, threshold, emit edges (i<<13)|j.
// 128x128 tile / 256 threads, 8x8 micro-tile, BK=32, fp32 FMA.
//
// LDS layout: [row][k] with quad-swizzle keyed on row>>3:
//   float index = row*32 + 4*(k4 ^ ((row>>3)&7)) + (k&3)
// Bank arithmetic (32 banks, pitch 32 floats = one full bank period):
//   A-read  (fixed r,k4): rows ty*8+r, 4 distinct ty/wave -> 4 addrs on 4
//           distinct bank-quads, 16-lane broadcast  -> conflict-free
//   B-read  (fixed c,k4): rows tx*8+c, 16 addrs, quad = k4^tx covers 0..7
//           twice -> 2 addrs/quad (2-way aliasing = free, m136)
//   staging write: 8 rows x 8 quads rectangular per wave -> uniform banks
// Per-thread swizzle base is shared by all 8 fragment rows (row>>3 = ty or
// tx), so inner loop = 2 addr calcs + 16 ds_read_b128 (imm offsets) + 256 FMA.
// ---------------------------------------------------------------------------
__global__ __launch_bounds__(256) void edge_kernel(
        const float* __restrict__ V,
        const float* __restrict__ thr_p,
        unsigned*    __restrict__ ec,
        unsigned*    __restrict__ edges) {
    const int bi = blockIdx.y;   // i-tile
    const int bj = blockIdx.x;   // j-tile
    if (bj < bi) return;         // upper triangle of tiles only

    __shared__ float As[128 * 32];
    __shared__ float Bs[128 * 32];

    const float thr = thr_p[0];
    const int tid = threadIdx.x;
    const int tx = tid & 15;          // j micro group (8 cols)
    const int ty = tid >> 4;          // i micro group (8 rows)
    const int i0 = bi * 128, j0 = bj * 128;

    float acc[8][8];
#pragma unroll
    for (int r = 0; r < 8; ++r)
#pragma unroll
        for (int c = 0; c < 8; ++c) acc[r][c] = 0.f;

    const int srow = tid >> 3;        // staging row within 32-row group
    const int sq   = tid & 7;         // staging quad (k4)

    for (int kc = 0; kc < DIM; kc += 32) {
        // ---- stage 128x32 fp32 tiles (swizzled) ----
#pragma unroll
        for (int p = 0; p < 4; ++p) {
            int row = srow + 32 * p;
            float4 va = *reinterpret_cast<const float4*>(
                &V[(size_t)(i0 + row) * DIM + kc + sq * 4]);
            float4 vb = *reinterpret_cast<const float4*>(
                &V[(size_t)(j0 + row) * DIM + kc + sq * 4]);
            int w = row * 32 + ((sq ^ ((row >> 3) & 7)) << 2);
            *reinterpret_cast<float4*>(&As[w]) = va;
            *reinterpret_cast<float4*>(&Bs[w]) = vb;
        }
        __syncthreads();

        // ---- compute: 8 k4-steps of 4 k each ----
#pragma unroll
        for (int k4 = 0; k4 < 8; ++k4) {
            const float* pA = &As[(ty * 8) * 32 + ((k4 ^ (ty & 7)) << 2)];
            const float* pB = &Bs[(tx * 8) * 32 + ((k4 ^ (tx & 7)) << 2)];
            float4 a[8], b[8];
#pragma unroll
            for (int r = 0; r < 8; ++r)
                a[r] = *reinterpret_cast<const float4*>(&pA[r * 32]);
#pragma unroll
            for (int c = 0; c < 8; ++c)
                b[c] = *reinterpret_cast<const float4*>(&pB[c * 32]);
#pragma unroll
            for (int r = 0; r < 8; ++r)
#pragma unroll
                for (int c = 0; c < 8; ++c) {
                    acc[r][c] = fmaf(a[r].x, b[c].x, acc[r][c]);
                    acc[r][c] = fmaf(a[r].y, b[c].y, acc[r][c]);
                    acc[r][c] = fmaf(a[r].z, b[c].z, acc[r][c]);
                    acc[r][c] = fmaf(a[r].w, b[c].w, acc[r][c]);
                }
        }
        __syncthreads();
    }

    // ---- emit edges (strict upper triangle) ----
#pragma unroll
    for (int r = 0; r < 8; ++r)
#pragma unroll
        for (int c = 0; c < 8; ++c) {
            int i = i0 + ty * 8 + r;
            int j = j0 + tx * 8 + c;
            if (j > i && acc[r][c] >= thr) {
                unsigned p = atomicAdd(ec, 1u);
                if (p < CAP) edges[p] = ((unsigned)i << 13) | (unsigned)j;
            }
        }
}

// ---------------------------------------------------------------------------
// Kernel 2: one block. Counting-sort edges by row i (LDS), then serial
// union-find in LDS replicating the reference's sequential merge order,
// then parallel root write-out.
// Exact-order guarantee: rows ascending; within a row, union direction is
// always parent[find(j)] = find(i), and find(i) is invariant within a row,
// so j-order inside a row does not matter.
// ---------------------------------------------------------------------------
__global__ __launch_bounds__(1024) void uf_kernel(
        const unsigned* __restrict__ ec,
        const unsigned* __restrict__ edges,
        int* __restrict__ out) {
    __shared__ unsigned cnt[NPTS];        // 32 KB: counts -> offsets
    __shared__ unsigned sedge[SORT_CAP];  // 32 KB: row-sorted edges
    __shared__ int      par[NPTS];        // 32 KB: union-find parents
    __shared__ int      wexc[17];

    const int tid  = threadIdx.x;
    const int lane = tid & 63;
    const int wid  = tid >> 6;

    unsigned EC = *ec;
    if (EC > CAP) EC = CAP;

    for (int t = tid; t < NPTS; t += 1024) { cnt[t] = 0u; par[t] = t; }
    __syncthreads();

    // histogram rows
    for (unsigned e = tid; e < EC; e += 1024)
        atomicAdd(&cnt[edges[e] >> 13], 1u);
    __syncthreads();

    // exclusive scan over 8192 counts (8 per thread, wave scan, block combine)
    unsigned v[8], s = 0;
    const unsigned base = (unsigned)tid * 8u;
#pragma unroll
    for (int q = 0; q < 8; ++q) { v[q] = cnt[base + q]; s += v[q]; }
    int inc = (int)s;
#pragma unroll
    for (int d = 1; d < 64; d <<= 1) {
        int u = __shfl_up(inc, d);
        if (lane >= d) inc += u;
    }
    if (lane == 63) wexc[wid + 1] = inc;
    if (tid == 0)   wexc[0] = 0;
    __syncthreads();
    if (tid == 0) {
        for (int w = 1; w <= 16; ++w) wexc[w] += wexc[w - 1];
    }
    __syncthreads();
    unsigned o = (unsigned)(wexc[wid] + inc - (int)s);
#pragma unroll
    for (int q = 0; q < 8; ++q) { cnt[base + q] = o; o += v[q]; }
    __syncthreads();

    // scatter into row-sorted order
    for (unsigned e = tid; e < EC; e += 1024) {
        unsigned key = edges[e];
        unsigned p = atomicAdd(&cnt[key >> 13], 1u);
        if (p < SORT_CAP) sedge[p] = key;
    }
    __syncthreads();

    // serial union-find, edges in ascending-row order
    unsigned SC = EC > SORT_CAP ? SORT_CAP : EC;
    if (tid == 0) {
        for (unsigned e = 0; e < SC; ++e) {
            unsigned key = sedge[e];
            int i = (int)(key >> 13);
            int j = (int)(key & 8191u);
            // dual-chain walk: overlap the two dependent LDS latency chains
            int ri = i, rj = j;
            int pi = par[ri], pj = par[rj];
            while (pi != ri || pj != rj) {
                ri = pi; rj = pj;
                pi = par[ri]; pj = par[rj];
            }
            if (rj != ri) par[rj] = ri;   // directed union into i's root
            par[i] = ri;                  // path compression (root-preserving)
            par[j] = ri;
        }
    }
    __syncthreads();

    // parallel root write-out (read-only finds)
    for (int t = tid; t < NPTS; t += 1024) {
        int r = t;
        while (par[r] != r) r = par[r];
        out[t] = r;
    }
}

extern "C" void kernel_launch(void* const* d_in, const int* in_sizes, int n_in,
                              void* d_out, int out_size, void* d_ws, size_t ws_size,
                              hipStream_t stream) {
    const float* V     = (const float*)d_in[0];
    const float* thr_p = (const float*)d_in[1];
    // d_in[2] (batch_size) provably does not affect the result (see analysis).

    unsigned* ec    = (unsigned*)d_ws;
    unsigned* edges = (unsigned*)((char*)d_ws + 64);
    int*      out   = (int*)d_out;

    hipLaunchKernelGGL(init_count, dim3(1), dim3(64), 0, stream, ec);
    hipLaunchKernelGGL(edge_kernel, dim3(64, 64), dim3(256), 0, stream,
                       V, thr_p, ec, edges);
    hipLaunchKernelGGL(uf_kernel, dim3(1), dim3(1024), 0, stream,
                       ec, edges, out);
}

// Round 3
// 175.805 us; speedup vs baseline: 4.7693x; 2.5404x over previous
//
#include <hip/hip_runtime.h>
#include <stdint.h>

#define NPTS 8192
#define DIM  256
#define CAP  32768      // edge capacity in workspace (expected ~1100 edges)
#define SORT_CAP 8192   // sorted-edge LDS capacity

typedef _Float16 f16x8 __attribute__((ext_vector_type(8)));
typedef float    f32x16 __attribute__((ext_vector_type(16)));

// ---------------------------------------------------------------------------
__global__ void init_count(unsigned* ec) {
    if (threadIdx.x == 0) *ec = 0u;
}

// ---------------------------------------------------------------------------
// Split V (fp32) -> Vh = fp16(v), Vl = fp16(4096*(v - Vh)).  Scaling by 4096
// keeps the residual in fp16 normal range (no denormal-flush risk in MFMA).
// ---------------------------------------------------------------------------
__global__ __launch_bounds__(256) void split_kernel(
        const float* __restrict__ V,
        _Float16* __restrict__ Vh,
        _Float16* __restrict__ Vl) {
    int t = blockIdx.x * 256 + threadIdx.x;        // 262144 threads * 8 elems
    const float4* src = reinterpret_cast<const float4*>(V) + (size_t)t * 2;
    float4 v0 = src[0], v1 = src[1];
    float vv[8] = {v0.x, v0.y, v0.z, v0.w, v1.x, v1.y, v1.z, v1.w};
    f16x8 h, l;
#pragma unroll
    for (int q = 0; q < 8; ++q) {
        _Float16 hh = (_Float16)vv[q];
        float rem = vv[q] - (float)hh;             // exact (Sterbenz)
        h[q] = hh;
        l[q] = (_Float16)(rem * 4096.0f);          // exact *2^12, then round
    }
    *reinterpret_cast<f16x8*>(Vh + (size_t)t * 8) = h;
    *reinterpret_cast<f16x8*>(Vl + (size_t)t * 8) = l;
}

// ---------------------------------------------------------------------------
__device__ __forceinline__ void gload_lds16(const void* g, void* l) {
    __builtin_amdgcn_global_load_lds(
        (const __attribute__((address_space(1))) void*)g,
        (__attribute__((address_space(3))) void*)l, 16, 0, 0);
}

// ---------------------------------------------------------------------------
// MFMA edge kernel: 128x128 tile / 4 waves (64x64 each, 2x2 of 32x32),
// v_mfma_f32_32x32x16_f16, KC=64 staged via global_load_lds with
// pre-swizzled global source (LDS stays linear; 16B-block XOR swizzle).
// sim = acc_h + acc_l/4096;  acc_h = sum ah*bh,  acc_l = sum ah*bl' + al'*bh.
// Correctness is independent of the MFMA A/B k-permutation: both operands
// use the identical (lane,elem)->k map, so the product set is the full dot.
// C/D layout (m74/m101): col = lane&31, row = (reg&3)+8*(reg>>2)+4*(lane>>5).
// ---------------------------------------------------------------------------
__global__ __launch_bounds__(256, 2) void edge_mfma(
        const _Float16* __restrict__ Vh,
        const _Float16* __restrict__ Vl,
        const float* __restrict__ thr_p,
        unsigned* __restrict__ ec,
        unsigned* __restrict__ edges) {
    const int bi = blockIdx.y, bj = blockIdx.x;
    if (bj < bi) return;                       // upper triangle of tiles

    __shared__ _Float16 L[4 * 128 * 64];       // Ah | Al | Bh | Bl = 64 KB

    const float thr = thr_p[0];
    const int tid  = threadIdx.x;
    const int lane = tid & 63;
    const int wid  = tid >> 6;
    const int wr = wid >> 1, wc = wid & 1;     // 2x2 wave grid
    const int i0 = bi * 128, j0 = bj * 128;

    f32x16 acc_h[2][2], acc_l[2][2];
#pragma unroll
    for (int t = 0; t < 2; ++t)
#pragma unroll
        for (int u = 0; u < 2; ++u) { acc_h[t][u] = 0.0f; acc_l[t][u] = 0.0f; }

    const int row_l = lane >> 3;               // 0..7 within 8-row stripe
    const int bphys = lane & 7;                // physical 16B block
    const int l31 = lane & 31, g = lane >> 5, l7 = lane & 7;

    for (int kc = 0; kc < DIM; kc += 64) {
        // ---- stage: each wave loads one 128x64 fp16 array (16 x 1KB) ----
#pragma unroll
        for (int q = 0; q < 16; ++q) {
            const int qq  = wid * 16 + q;      // 0..63
            const int arr = qq >> 4;           // 0:Ah 1:Al 2:Bh 3:Bl
            const int ins = qq & 15;
            const int row = ins * 8 + row_l;   // row&7 == row_l
            const int blk = bphys ^ row_l;     // logical 16B block for this slot
            const _Float16* srcb = (arr & 1) ? Vl : Vh;
            const int grow = ((arr & 2) ? j0 : i0) + row;
            gload_lds16(srcb + ((size_t)grow * DIM + kc + blk * 8),
                        &L[arr * 8192 + ins * 512]);
        }
        __syncthreads();

        // ---- 4 MFMA K-steps of 16 ----
#pragma unroll
        for (int s = 0; s < 4; ++s) {
            const int xa = (((s * 2 + g) ^ l7) << 3);   // swizzled k-offset
            f16x8 ah[2], al[2], bh[2], bl[2];
#pragma unroll
            for (int t = 0; t < 2; ++t) {
                const int ra = (wr * 64 + t * 32 + l31) * 64;
                ah[t] = *(const f16x8*)&L[ra + xa];
                al[t] = *(const f16x8*)&L[8192 + ra + xa];
                const int rb = (wc * 64 + t * 32 + l31) * 64;
                bh[t] = *(const f16x8*)&L[16384 + rb + xa];
                bl[t] = *(const f16x8*)&L[24576 + rb + xa];
            }
#pragma unroll
            for (int t = 0; t < 2; ++t)
#pragma unroll
                for (int u = 0; u < 2; ++u) {
                    acc_h[t][u] = __builtin_amdgcn_mfma_f32_32x32x16_f16(
                        ah[t], bh[u], acc_h[t][u], 0, 0, 0);
                    acc_l[t][u] = __builtin_amdgcn_mfma_f32_32x32x16_f16(
                        al[t], bh[u], acc_l[t][u], 0, 0, 0);
                    acc_l[t][u] = __builtin_amdgcn_mfma_f32_32x32x16_f16(
                        ah[t], bl[u], acc_l[t][u], 0, 0, 0);
                }
        }
        __syncthreads();
    }

    // ---- epilogue: combine splits, threshold, emit edges ----
    const int rbase = 4 * (lane >> 5);
#pragma unroll
    for (int t = 0; t < 2; ++t)
#pragma unroll
        for (int u = 0; u < 2; ++u)
#pragma unroll
            for (int reg = 0; reg < 16; ++reg) {
                float sim = acc_h[t][u][reg]
                          + acc_l[t][u][reg] * (1.0f / 4096.0f);
                int row = (reg & 3) + 8 * (reg >> 2) + rbase;
                int i = i0 + wr * 64 + t * 32 + row;
                int j = j0 + wc * 64 + u * 32 + l31;
                if (j > i && sim >= thr) {
                    unsigned p = atomicAdd(ec, 1u);
                    if (p < CAP) edges[p] = ((unsigned)i << 13) | (unsigned)j;
                }
            }
}

// ---------------------------------------------------------------------------
// Fallback fp32 edge kernel (round-2 version) in case d_ws is too small for
// the fp16 split arrays.
// ---------------------------------------------------------------------------
__global__ __launch_bounds__(256) void edge_kernel(
        const float* __restrict__ V,
        const float* __restrict__ thr_p,
        unsigned*    __restrict__ ec,
        unsigned*    __restrict__ edges) {
    const int bi = blockIdx.y;
    const int bj = blockIdx.x;
    if (bj < bi) return;

    __shared__ float As[128 * 32];
    __shared__ float Bs[128 * 32];

    const float thr = thr_p[0];
    const int tid = threadIdx.x;
    const int tx = tid & 15;
    const int ty = tid >> 4;
    const int i0 = bi * 128, j0 = bj * 128;

    float acc[8][8];
#pragma unroll
    for (int r = 0; r < 8; ++r)
#pragma unroll
        for (int c = 0; c < 8; ++c) acc[r][c] = 0.f;

    const int srow = tid >> 3;
    const int sq   = tid & 7;

    for (int kc = 0; kc < DIM; kc += 32) {
#pragma unroll
        for (int p = 0; p < 4; ++p) {
            int row = srow + 32 * p;
            float4 va = *reinterpret_cast<const float4*>(
                &V[(size_t)(i0 + row) * DIM + kc + sq * 4]);
            float4 vb = *reinterpret_cast<const float4*>(
                &V[(size_t)(j0 + row) * DIM + kc + sq * 4]);
            int w = row * 32 + ((sq ^ ((row >> 3) & 7)) << 2);
            *reinterpret_cast<float4*>(&As[w]) = va;
            *reinterpret_cast<float4*>(&Bs[w]) = vb;
        }
        __syncthreads();

#pragma unroll
        for (int k4 = 0; k4 < 8; ++k4) {
            const float* pA = &As[(ty * 8) * 32 + ((k4 ^ (ty & 7)) << 2)];
            const float* pB = &Bs[(tx * 8) * 32 + ((k4 ^ (tx & 7)) << 2)];
            float4 a[8], b[8];
#pragma unroll
            for (int r = 0; r < 8; ++r)
                a[r] = *reinterpret_cast<const float4*>(&pA[r * 32]);
#pragma unroll
            for (int c = 0; c < 8; ++c)
                b[c] = *reinterpret_cast<const float4*>(&pB[c * 32]);
#pragma unroll
            for (int r = 0; r < 8; ++r)
#pragma unroll
                for (int c = 0; c < 8; ++c) {
                    acc[r][c] = fmaf(a[r].x, b[c].x, acc[r][c]);
                    acc[r][c] = fmaf(a[r].y, b[c].y, acc[r][c]);
                    acc[r][c] = fmaf(a[r].z, b[c].z, acc[r][c]);
                    acc[r][c] = fmaf(a[r].w, b[c].w, acc[r][c]);
                }
        }
        __syncthreads();
    }

#pragma unroll
    for (int r = 0; r < 8; ++r)
#pragma unroll
        for (int c = 0; c < 8; ++c) {
            int i = i0 + ty * 8 + r;
            int j = j0 + tx * 8 + c;
            if (j > i && acc[r][c] >= thr) {
                unsigned p = atomicAdd(ec, 1u);
                if (p < CAP) edges[p] = ((unsigned)i << 13) | (unsigned)j;
            }
        }
}

// ---------------------------------------------------------------------------
// Kernel 2: counting-sort edges by row, parallel fresh-edge elimination,
// serial union-find replay for the remainder, parallel root write-out.
//
// Fresh edge = both endpoints appear for the first time at position e in the
// sorted order -> at its sequential execution time both are singletons, so
// the union is exactly par[j] = i, and fresh edges are pairwise node-disjoint
// (a shared node would make the later edge non-fresh) -> parallel-applicable.
// ---------------------------------------------------------------------------
__global__ __launch_bounds__(1024) void uf_kernel(
        const unsigned* __restrict__ ec,
        const unsigned* __restrict__ edges,
        int* __restrict__ out) {
    __shared__ unsigned cnt[NPTS];            // counts -> offsets -> firstE
    __shared__ unsigned sedge[SORT_CAP + 8];  // row-sorted edges (+pad)
    __shared__ int      par[NPTS];
    __shared__ int      wexc[17];

    const int tid  = threadIdx.x;
    const int lane = tid & 63;
    const int wid  = tid >> 6;

    unsigned EC = *ec;
    if (EC > CAP) EC = CAP;

    for (int t = tid; t < NPTS; t += 1024) { cnt[t] = 0u; par[t] = t; }
    __syncthreads();

    // histogram rows
    for (unsigned e = tid; e < EC; e += 1024)
        atomicAdd(&cnt[edges[e] >> 13], 1u);
    __syncthreads();

    // exclusive scan over 8192 counts
    unsigned v[8], s = 0;
    const unsigned base = (unsigned)tid * 8u;
#pragma unroll
    for (int q = 0; q < 8; ++q) { v[q] = cnt[base + q]; s += v[q]; }
    int inc = (int)s;
#pragma unroll
    for (int d = 1; d < 64; d <<= 1) {
        int u = __shfl_up(inc, d);
        if (lane >= d) inc += u;
    }
    if (lane == 63) wexc[wid + 1] = inc;
    if (tid == 0)   wexc[0] = 0;
    __syncthreads();
    if (tid == 0)
        for (int w = 1; w <= 16; ++w) wexc[w] += wexc[w - 1];
    __syncthreads();
    unsigned o = (unsigned)(wexc[wid] + inc - (int)s);
#pragma unroll
    for (int q = 0; q < 8; ++q) { cnt[base + q] = o; o += v[q]; }
    __syncthreads();

    // scatter into row-sorted order (j-order within a row is irrelevant)
    for (unsigned e = tid; e < EC; e += 1024) {
        unsigned key = edges[e];
        unsigned p = atomicAdd(&cnt[key >> 13], 1u);
        if (p < SORT_CAP) sedge[p] = key;
    }
    __syncthreads();

    unsigned SC = EC > SORT_CAP ? SORT_CAP : EC;

    // ---- fresh-edge detection: reuse cnt as firstE ----
    for (int t = tid; t < NPTS; t += 1024) cnt[t] = 0xFFFFFFFFu;
    if (tid < 8) sedge[SC + tid] = 0x80000000u;    // pad = flagged
    __syncthreads();
    for (unsigned e = tid; e < SC; e += 1024) {
        unsigned key = sedge[e];
        atomicMin(&cnt[key >> 13], e);
        atomicMin(&cnt[key & 8191u], e);
    }
    __syncthreads();
    for (unsigned e = tid; e < SC; e += 1024) {
        unsigned key = sedge[e];
        unsigned i = key >> 13, j = key & 8191u;
        if (cnt[i] == e && cnt[j] == e) {          // both endpoints fresh
            par[j] = (int)i;                       // exact sequential effect
            sedge[e] = key | 0x80000000u;          // mark processed
        }
    }
    __syncthreads();

    // ---- serial replay of remaining edges (batch-8 prefetch) ----
    if (tid == 0) {
        for (unsigned b = 0; b < SC; b += 8) {
            unsigned kb[8];
#pragma unroll
            for (int q = 0; q < 8; ++q) kb[q] = sedge[b + q];
#pragma unroll
            for (int q = 0; q < 8; ++q) {
                unsigned key = kb[q];
                if (key & 0x80000000u) continue;
                int i = (int)(key >> 13);
                int j = (int)(key & 8191u);
                int ri = i, rj = j;
                int pi = par[ri], pj = par[rj];
                while (pi != ri || pj != rj) {
                    ri = pi; rj = pj;
                    pi = par[ri]; pj = par[rj];
                }
                if (rj != ri) par[rj] = ri;        // union into i's root
                par[i] = ri;                       // path compression
                par[j] = ri;
            }
        }
    }
    __syncthreads();

    // parallel root write-out
    for (int t = tid; t < NPTS; t += 1024) {
        int r = t;
        while (par[r] != r) r = par[r];
        out[t] = r;
    }
}

extern "C" void kernel_launch(void* const* d_in, const int* in_sizes, int n_in,
                              void* d_out, int out_size, void* d_ws, size_t ws_size,
                              hipStream_t stream) {
    const float* V     = (const float*)d_in[0];
    const float* thr_p = (const float*)d_in[1];
    // d_in[2] (batch_size) provably does not affect the result.

    unsigned* ec    = (unsigned*)d_ws;
    unsigned* edges = (unsigned*)((char*)d_ws + 64);
    int*      out   = (int*)d_out;

    const size_t vhOff = 1u << 20;
    const size_t vN    = (size_t)NPTS * DIM;              // 2M halves = 4 MB
    const size_t need  = vhOff + 2 * vN * sizeof(_Float16) + 65536;

    hipLaunchKernelGGL(init_count, dim3(1), dim3(64), 0, stream, ec);

    if (ws_size >= need) {
        _Float16* Vh = (_Float16*)((char*)d_ws + vhOff);
        _Float16* Vl = Vh + vN;
        hipLaunchKernelGGL(split_kernel, dim3(1024), dim3(256), 0, stream,
                           V, Vh, Vl);
        hipLaunchKernelGGL(edge_mfma, dim3(64, 64), dim3(256), 0, stream,
                           Vh, Vl, thr_p, ec, edges);
    } else {
        hipLaunchKernelGGL(edge_kernel, dim3(64, 64), dim3(256), 0, stream,
                           V, thr_p, ec, edges);
    }
    hipLaunchKernelGGL(uf_kernel, dim3(1), dim3(1024), 0, stream,
                       ec, edges, out);
}

// Round 5
// 120.140 us; speedup vs baseline: 6.9790x; 1.4633x over previous
//
#include <hip/hip_runtime.h>
#include <stdint.h>

#define NPTS 8192
#define DIM  256
#define CAP  32768       // global edge/candidate capacity (expected ~1100 / ~300)
#define LDSE 8192        // in-LDS edge capacity for the UF kernel
#define BAND 2.0e-3f     // > bound 9.9e-4 on |sim_exact - sim_fp16h| (unit rows)

typedef _Float16 f16x8  __attribute__((ext_vector_type(8)));
typedef float    f32x16 __attribute__((ext_vector_type(16)));

// ws layout: [0..64)   ctr: ctr[0]=edge count, ctr[1]=candidate count
//            [64..)        edges (CAP u32)
//            [256K..)      cand  (CAP u32)
//            [1M..)        Vh    (4 MB fp16)

// ---------------------------------------------------------------------------
// Convert V fp32 -> fp16 high half; block 0 zeroes the counters.
// ---------------------------------------------------------------------------
__global__ __launch_bounds__(256) void convert_kernel(
        const float* __restrict__ V, _Float16* __restrict__ Vh,
        unsigned* __restrict__ ctr) {
    if (blockIdx.x == 0 && threadIdx.x == 0) { ctr[0] = 0u; ctr[1] = 0u; }
    size_t t = (size_t)blockIdx.x * 256 + threadIdx.x;   // 262144 threads
    const float4* src = reinterpret_cast<const float4*>(V) + t * 2;
    float4 v0 = src[0], v1 = src[1];
    f16x8 h;
    h[0] = (_Float16)v0.x; h[1] = (_Float16)v0.y;
    h[2] = (_Float16)v0.z; h[3] = (_Float16)v0.w;
    h[4] = (_Float16)v1.x; h[5] = (_Float16)v1.y;
    h[6] = (_Float16)v1.z; h[7] = (_Float16)v1.w;
    *reinterpret_cast<f16x8*>(Vh + t * 8) = h;
}

__global__ void init_count(unsigned* ctr) {
    if (threadIdx.x == 0) { ctr[0] = 0u; ctr[1] = 0u; }
}

// ---------------------------------------------------------------------------
__device__ __forceinline__ void gload_lds16(const void* g, void* l) {
    __builtin_amdgcn_global_load_lds(
        (const __attribute__((address_space(1))) void*)g,
        (__attribute__((address_space(3))) void*)l, 16, 0, 0);
}

// ---------------------------------------------------------------------------
// h-only MFMA edge kernel. 128x128 tile / 4 waves (64x64 each, 2x2 of 32x32),
// v_mfma_f32_32x32x16_f16, KC=64, global_load_lds with pre-swizzled source.
// Classification: sim >= thr+BAND -> sure edge; sim >= thr-BAND -> candidate.
// 1D triangular grid (2080 blocks), no wasted lower-triangle dispatches.
// C/D layout (m74/m101): col = lane&31, row = (reg&3)+8*(reg>>2)+4*(lane>>5).
// ---------------------------------------------------------------------------
__global__ __launch_bounds__(256, 4) void edge_mfma(
        const _Float16* __restrict__ Vh,
        const float* __restrict__ thr_p,
        unsigned* __restrict__ ctr,
        unsigned* __restrict__ edges,
        unsigned* __restrict__ cand) {
    // decode triangular tile index: off(b) = 64b - b(b-1)/2
    int t = blockIdx.x;
    int bi = (int)(64.5f - sqrtf(64.5f * 64.5f - 2.0f * (float)t));
    while (bi * 64 - (bi * (bi - 1)) / 2 > t) --bi;
    while ((bi + 1) * 64 - ((bi + 1) * bi) / 2 <= t) ++bi;
    int bj = bi + (t - (bi * 64 - (bi * (bi - 1)) / 2));

    __shared__ _Float16 L[2 * 128 * 64];       // Ah | Bh = 32 KB

    const float thr = thr_p[0];
    const float hi = thr + BAND, lo = thr - BAND;
    const int tid  = threadIdx.x;
    const int lane = tid & 63;
    const int wid  = tid >> 6;
    const int wr = wid >> 1, wc = wid & 1;     // 2x2 wave grid
    const int i0 = bi * 128, j0 = bj * 128;

    f32x16 acc[2][2];
#pragma unroll
    for (int a = 0; a < 2; ++a)
#pragma unroll
        for (int b = 0; b < 2; ++b) acc[a][b] = 0.0f;

    const int row_l = lane >> 3;               // 0..7
    const int bphys = lane & 7;                // physical 16B block
    const int l31 = lane & 31, g = lane >> 5, l7 = lane & 7;

    for (int kc = 0; kc < DIM; kc += 64) {
        // ---- stage Ah,Bh: 32 x 1KB instances / 4 waves = 8 per wave ----
#pragma unroll
        for (int q = 0; q < 8; ++q) {
            const int qq  = wid * 8 + q;       // 0..31
            const int arr = qq >> 4;           // 0:Ah 1:Bh
            const int ins = qq & 15;
            const int row = ins * 8 + row_l;
            const int blk = bphys ^ row_l;     // pre-swizzled global source
            const int grow = (arr ? j0 : i0) + row;
            gload_lds16(Vh + ((size_t)grow * DIM + kc + blk * 8),
                        &L[arr * 8192 + ins * 512]);
        }
        __syncthreads();

        // ---- 4 MFMA K-steps of 16 ----
#pragma unroll
        for (int s = 0; s < 4; ++s) {
            const int xa = (((s * 2 + g) ^ l7) << 3);
            f16x8 ah[2], bh[2];
#pragma unroll
            for (int a = 0; a < 2; ++a) {
                ah[a] = *(const f16x8*)&L[(wr * 64 + a * 32 + l31) * 64 + xa];
                bh[a] = *(const f16x8*)&L[8192 + (wc * 64 + a * 32 + l31) * 64 + xa];
            }
#pragma unroll
            for (int a = 0; a < 2; ++a)
#pragma unroll
                for (int b = 0; b < 2; ++b)
                    acc[a][b] = __builtin_amdgcn_mfma_f32_32x32x16_f16(
                        ah[a], bh[b], acc[a][b], 0, 0, 0);
        }
        __syncthreads();
    }

    // ---- epilogue: banded classification ----
    const int rbase = 4 * (lane >> 5);
#pragma unroll
    for (int a = 0; a < 2; ++a)
#pragma unroll
        for (int b = 0; b < 2; ++b)
#pragma unroll
            for (int reg = 0; reg < 16; ++reg) {
                float sim = acc[a][b][reg];
                int row = (reg & 3) + 8 * (reg >> 2) + rbase;
                int i = i0 + wr * 64 + a * 32 + row;
                int j = j0 + wc * 64 + b * 32 + l31;
                if (j > i && sim >= lo) {
                    unsigned key = ((unsigned)i << 13) | (unsigned)j;
                    if (sim >= hi) {
                        unsigned p = atomicAdd(&ctr[0], 1u);
                        if (p < CAP) edges[p] = key;
                    } else {
                        unsigned p = atomicAdd(&ctr[1], 1u);
                        if (p < CAP) cand[p] = key;
                    }
                }
            }
}

// ---------------------------------------------------------------------------
// fp32 fallback (exact path, no candidates) if ws is too small for Vh.
// ---------------------------------------------------------------------------
__global__ __launch_bounds__(256) void edge_kernel(
        const float* __restrict__ V,
        const float* __restrict__ thr_p,
        unsigned*    __restrict__ ctr,
        unsigned*    __restrict__ edges) {
    const int bi = blockIdx.y, bj = blockIdx.x;
    if (bj < bi) return;

    __shared__ float As[128 * 32];
    __shared__ float Bs[128 * 32];

    const float thr = thr_p[0];
    const int tid = threadIdx.x;
    const int tx = tid & 15, ty = tid >> 4;
    const int i0 = bi * 128, j0 = bj * 128;

    float acc[8][8];
#pragma unroll
    for (int r = 0; r < 8; ++r)
#pragma unroll
        for (int c = 0; c < 8; ++c) acc[r][c] = 0.f;

    const int srow = tid >> 3, sq = tid & 7;

    for (int kc = 0; kc < DIM; kc += 32) {
#pragma unroll
        for (int p = 0; p < 4; ++p) {
            int row = srow + 32 * p;
            float4 va = *reinterpret_cast<const float4*>(
                &V[(size_t)(i0 + row) * DIM + kc + sq * 4]);
            float4 vb = *reinterpret_cast<const float4*>(
                &V[(size_t)(j0 + row) * DIM + kc + sq * 4]);
            int w = row * 32 + ((sq ^ ((row >> 3) & 7)) << 2);
            *reinterpret_cast<float4*>(&As[w]) = va;
            *reinterpret_cast<float4*>(&Bs[w]) = vb;
        }
        __syncthreads();
#pragma unroll
        for (int k4 = 0; k4 < 8; ++k4) {
            const float* pA = &As[(ty * 8) * 32 + ((k4 ^ (ty & 7)) << 2)];
            const float* pB = &Bs[(tx * 8) * 32 + ((k4 ^ (tx & 7)) << 2)];
            float4 a[8], b[8];
#pragma unroll
            for (int r = 0; r < 8; ++r)
                a[r] = *reinterpret_cast<const float4*>(&pA[r * 32]);
#pragma unroll
            for (int c = 0; c < 8; ++c)
                b[c] = *reinterpret_cast<const float4*>(&pB[c * 32]);
#pragma unroll
            for (int r = 0; r < 8; ++r)
#pragma unroll
                for (int c = 0; c < 8; ++c) {
                    acc[r][c] = fmaf(a[r].x, b[c].x, acc[r][c]);
                    acc[r][c] = fmaf(a[r].y, b[c].y, acc[r][c]);
                    acc[r][c] = fmaf(a[r].z, b[c].z, acc[r][c]);
                    acc[r][c] = fmaf(a[r].w, b[c].w, acc[r][c]);
                }
        }
        __syncthreads();
    }
#pragma unroll
    for (int r = 0; r < 8; ++r)
#pragma unroll
        for (int c = 0; c < 8; ++c) {
            int i = i0 + ty * 8 + r;
            int j = j0 + tx * 8 + c;
            if (j > i && acc[r][c] >= thr) {
                unsigned p = atomicAdd(&ctr[0], 1u);
                if (p < CAP) edges[p] = ((unsigned)i << 13) | (unsigned)j;
            }
        }
}

// ---------------------------------------------------------------------------
// UF kernel (one block, 1024 threads):
//   phase 0: fp64 re-resolution of banded candidates (wave per candidate)
//   phase 1: parallel winner-rounds exact replay of the sequential merge
//   phase 2: parallel root write-out
//
// Winner-rounds correctness: per round each live edge e computes its current
// roots (ri,rj) and atomicMin's its packed key into slot[ri], slot[rj].
// e applies iff it holds both slots (= no smaller live edge touches either
// root). Then (a) every live edge f<e is root-disjoint from e, and disjoint
// unions commute, so e's evaluation state restricted to its roots equals its
// sequential state -> par[rj]=ri is the exact sequential effect; (b) winners
// are pairwise node-disjoint (shared node => shared root => same slot), so
// parallel application + compression is race-free; (c) the globally smallest
// live key always wins both slots -> >=1 retire/round -> termination.
// ---------------------------------------------------------------------------
__global__ __launch_bounds__(1024) void uf_kernel(
        const unsigned* __restrict__ ctr,
        const unsigned* __restrict__ edges,
        const unsigned* __restrict__ cand,
        const float* __restrict__ V,
        const float* __restrict__ thr_p,
        int* __restrict__ out) {
    __shared__ int      par[NPTS];        // 32 KB
    __shared__ unsigned slot[NPTS];       // 32 KB
    __shared__ unsigned sedge[LDSE];      // 32 KB
    __shared__ unsigned nE_s, nRem_s;

    const int tid  = threadIdx.x;
    const int lane = tid & 63;
    const int wv   = tid >> 6;            // 16 waves

    unsigned EC = ctr[0]; if (EC > LDSE) EC = LDSE;
    unsigned CC = ctr[1]; if (CC > CAP)  CC = CAP;

    for (int t = tid; t < NPTS; t += 1024) { par[t] = t; slot[t] = 0xFFFFFFFFu; }
    if (tid == 0) nE_s = EC;
    __syncthreads();

    // load sure edges into LDS
    for (unsigned e = tid; e < EC; e += 1024) sedge[e] = edges[e];

    // candidate re-resolution in fp64 (exact vs band): wave per candidate
    const float thr = thr_p[0];
    for (unsigned c = wv; c < CC; c += 16) {
        unsigned key = cand[c];
        int i = (int)(key >> 13), j = (int)(key & 8191u);
        const float* vi = V + (size_t)i * DIM;
        const float* vj = V + (size_t)j * DIM;
        double sum = 0.0;
        for (int k = lane; k < DIM; k += 64)
            sum += (double)vi[k] * (double)vj[k];
#pragma unroll
        for (int d = 32; d; d >>= 1) sum += __shfl_down(sum, d);
        if (lane == 0 && sum >= (double)thr) {
            unsigned p = atomicAdd(&nE_s, 1u);
            if (p < LDSE) sedge[p] = key;
        }
    }
    __syncthreads();

    unsigned nE = nE_s; if (nE > LDSE) nE = LDSE;
    if (tid == 0) nRem_s = nE;
    __syncthreads();

    volatile int* vpar = par;

    // ---- winner rounds ----
    while (true) {
        unsigned rem = nRem_s;            // stable: last write pre-barrier
        if (rem == 0) break;
        // Phase A: finds against round-start state + slot bids
        for (unsigned e = tid; e < nE; e += 1024) {
            unsigned key = sedge[e];
            if (key & 0x80000000u) continue;
            int ri = (int)(key >> 13), rj = (int)(key & 8191u);
            int p;
            while ((p = vpar[ri]) != ri) ri = p;
            while ((p = vpar[rj]) != rj) rj = p;
            atomicMin(&slot[ri], key);
            atomicMin(&slot[rj], key);
        }
        __syncthreads();
        // Phase B: winners apply (node-disjoint; concurrent finds safe)
        for (unsigned e = tid; e < nE; e += 1024) {
            unsigned key = sedge[e];
            if (key & 0x80000000u) continue;
            int i = (int)(key >> 13), j = (int)(key & 8191u);
            int ri = i, rj = j, p;
            while ((p = vpar[ri]) != ri) ri = p;
            while ((p = vpar[rj]) != rj) rj = p;
            if (slot[ri] == key && slot[rj] == key) {
                if (ri != rj) { par[rj] = ri; par[i] = ri; par[j] = ri; }
                sedge[e] = key | 0x80000000u;
                atomicSub(&nRem_s, 1u);
            }
        }
        __syncthreads();
        // Phase C: clear slots
        for (int t = tid; t < NPTS; t += 1024) slot[t] = 0xFFFFFFFFu;
        __syncthreads();
    }

    // ---- root write-out ----
    for (int t = tid; t < NPTS; t += 1024) {
        int r = t, p;
        while ((p = par[r]) != r) r = p;
        out[t] = r;
    }
}

extern "C" void kernel_launch(void* const* d_in, const int* in_sizes, int n_in,
                              void* d_out, int out_size, void* d_ws, size_t ws_size,
                              hipStream_t stream) {
    const float* V     = (const float*)d_in[0];
    const float* thr_p = (const float*)d_in[1];
    // d_in[2] (batch_size) provably does not affect the result.

    unsigned* ctr   = (unsigned*)d_ws;
    unsigned* edges = (unsigned*)((char*)d_ws + 64);
    unsigned* cand  = (unsigned*)((char*)d_ws + (256u << 10));
    int*      out   = (int*)d_out;

    const size_t vhOff = 1u << 20;
    const size_t vN    = (size_t)NPTS * DIM;
    const size_t need  = vhOff + vN * sizeof(_Float16) + 65536;

    if (ws_size >= need) {
        _Float16* Vh = (_Float16*)((char*)d_ws + vhOff);
        hipLaunchKernelGGL(convert_kernel, dim3(1024), dim3(256), 0, stream,
                           V, Vh, ctr);
        hipLaunchKernelGGL(edge_mfma, dim3(2080), dim3(256), 0, stream,
                           Vh, thr_p, ctr, edges, cand);
    } else {
        hipLaunchKernelGGL(init_count, dim3(1), dim3(64), 0, stream, ctr);
        hipLaunchKernelGGL(edge_kernel, dim3(64, 64), dim3(256), 0, stream,
                           V, thr_p, ctr, edges);
    }
    hipLaunchKernelGGL(uf_kernel, dim3(1), dim3(1024), 0, stream,
                       ctr, edges, cand, V, thr_p, out);
}

// Round 6
// 99.679 us; speedup vs baseline: 8.4116x; 1.2053x over previous
//
#include <hip/hip_runtime.h>
#include <stdint.h>

#define NPTS 8192
#define DIM  256
#define CAP  32768       // global edge capacity (expected ~1100)
#define LDSE 8192        // in-LDS edge capacity for the UF kernel
#define IBCAP 256        // per-block in-band candidate capacity
#define BAND 2.0e-3f     // > bound ~1.05e-3 on |sim_exact - sim_fp16h| (unit rows)

typedef _Float16 f16x8  __attribute__((ext_vector_type(8)));
typedef float    f32x16 __attribute__((ext_vector_type(16)));

// ws layout: [0..64)  ctr: ctr[0]=edge count
//            [64..)   edges (CAP u32)
//            [1M..)   Vh    (4 MB fp16)

// ---------------------------------------------------------------------------
// Convert V fp32 -> fp16 high half (RTNE); block 0 zeroes the counter.
// ---------------------------------------------------------------------------
__global__ __launch_bounds__(256) void convert_kernel(
        const float* __restrict__ V, _Float16* __restrict__ Vh,
        unsigned* __restrict__ ctr) {
    if (blockIdx.x == 0 && threadIdx.x == 0) { ctr[0] = 0u; ctr[1] = 0u; }
    size_t t = (size_t)blockIdx.x * 256 + threadIdx.x;   // 262144 threads
    const float4* src = reinterpret_cast<const float4*>(V) + t * 2;
    float4 v0 = src[0], v1 = src[1];
    f16x8 h;
    h[0] = (_Float16)v0.x; h[1] = (_Float16)v0.y;
    h[2] = (_Float16)v0.z; h[3] = (_Float16)v0.w;
    h[4] = (_Float16)v1.x; h[5] = (_Float16)v1.y;
    h[6] = (_Float16)v1.z; h[7] = (_Float16)v1.w;
    *reinterpret_cast<f16x8*>(Vh + t * 8) = h;
}

__global__ void init_count(unsigned* ctr) {
    if (threadIdx.x == 0) { ctr[0] = 0u; ctr[1] = 0u; }
}

// ---------------------------------------------------------------------------
__device__ __forceinline__ void gload_lds16(const void* g, void* l) {
    __builtin_amdgcn_global_load_lds(
        (const __attribute__((address_space(1))) void*)g,
        (__attribute__((address_space(3))) void*)l, 16, 0, 0);
}

// ---------------------------------------------------------------------------
// h-only MFMA edge kernel. 128x128 tile / 4 waves (64x64 each, 2x2 of 32x32),
// v_mfma_f32_32x32x16_f16, KC=64, global_load_lds with pre-swizzled source.
// Classification: sim >= thr+BAND -> sure edge; |sim-thr| < BAND -> deferred
// to an in-block LDS list, re-resolved exactly in fp64 after acc regs die.
// 1D triangular grid (2080 blocks).
// C/D layout (m74/m101): col = lane&31, row = (reg&3)+8*(reg>>2)+4*(lane>>5).
// ---------------------------------------------------------------------------
__global__ __launch_bounds__(256, 4) void edge_mfma(
        const _Float16* __restrict__ Vh,
        const float* __restrict__ V,
        const float* __restrict__ thr_p,
        unsigned* __restrict__ ctr,
        unsigned* __restrict__ edges) {
    // decode triangular tile index: off(b) = 64b - b(b-1)/2
    int t = blockIdx.x;
    int bi = (int)(64.5f - sqrtf(64.5f * 64.5f - 2.0f * (float)t));
    while (bi * 64 - (bi * (bi - 1)) / 2 > t) --bi;
    while ((bi + 1) * 64 - ((bi + 1) * bi) / 2 <= t) ++bi;
    int bj = bi + (t - (bi * 64 - (bi * (bi - 1)) / 2));

    __shared__ _Float16 L[2 * 128 * 64];       // Ah | Bh = 32 KB
    __shared__ unsigned ibl[IBCAP];            // in-band candidate keys
    __shared__ unsigned ibn;

    const float thr = thr_p[0];
    const float hi = thr + BAND, lo = thr - BAND;
    const int tid  = threadIdx.x;
    const int lane = tid & 63;
    const int wid  = tid >> 6;
    const int wr = wid >> 1, wc = wid & 1;     // 2x2 wave grid
    const int i0 = bi * 128, j0 = bj * 128;

    if (tid == 0) ibn = 0u;

    f32x16 acc[2][2];
#pragma unroll
    for (int a = 0; a < 2; ++a)
#pragma unroll
        for (int b = 0; b < 2; ++b) acc[a][b] = 0.0f;

    const int row_l = lane >> 3;               // 0..7
    const int bphys = lane & 7;                // physical 16B block
    const int l31 = lane & 31, g = lane >> 5, l7 = lane & 7;

    for (int kc = 0; kc < DIM; kc += 64) {
        // ---- stage Ah,Bh: 32 x 1KB instances / 4 waves = 8 per wave ----
#pragma unroll
        for (int q = 0; q < 8; ++q) {
            const int qq  = wid * 8 + q;       // 0..31
            const int arr = qq >> 4;           // 0:Ah 1:Bh
            const int ins = qq & 15;
            const int row = ins * 8 + row_l;
            const int blk = bphys ^ row_l;     // pre-swizzled global source
            const int grow = (arr ? j0 : i0) + row;
            gload_lds16(Vh + ((size_t)grow * DIM + kc + blk * 8),
                        &L[arr * 8192 + ins * 512]);
        }
        __syncthreads();

        // ---- 4 MFMA K-steps of 16 ----
#pragma unroll
        for (int s = 0; s < 4; ++s) {
            const int xa = (((s * 2 + g) ^ l7) << 3);
            f16x8 ah[2], bh[2];
#pragma unroll
            for (int a = 0; a < 2; ++a) {
                ah[a] = *(const f16x8*)&L[(wr * 64 + a * 32 + l31) * 64 + xa];
                bh[a] = *(const f16x8*)&L[8192 + (wc * 64 + a * 32 + l31) * 64 + xa];
            }
#pragma unroll
            for (int a = 0; a < 2; ++a)
#pragma unroll
                for (int b = 0; b < 2; ++b)
                    acc[a][b] = __builtin_amdgcn_mfma_f32_32x32x16_f16(
                        ah[a], bh[b], acc[a][b], 0, 0, 0);
        }
        __syncthreads();
    }

    // ---- epilogue pass 1: classify; sure edges emit, in-band defer ----
    const int rbase = 4 * (lane >> 5);
#pragma unroll
    for (int a = 0; a < 2; ++a)
#pragma unroll
        for (int b = 0; b < 2; ++b)
#pragma unroll
            for (int reg = 0; reg < 16; ++reg) {
                float sim = acc[a][b][reg];
                int row = (reg & 3) + 8 * (reg >> 2) + rbase;
                int i = i0 + wr * 64 + a * 32 + row;
                int j = j0 + wc * 64 + b * 32 + l31;
                if (j > i && sim >= lo) {
                    unsigned key = ((unsigned)i << 13) | (unsigned)j;
                    if (sim >= hi) {
                        unsigned p = atomicAdd(&ctr[0], 1u);
                        if (p < CAP) edges[p] = key;
                    } else {
                        unsigned p = atomicAdd(&ibn, 1u);
                        if (p < IBCAP) ibl[p] = key;
                    }
                }
            }
    __syncthreads();

    // ---- epilogue pass 2: exact fp64 re-resolution (acc regs dead) ----
    unsigned nib = ibn; if (nib > IBCAP) nib = IBCAP;
    const double thrd = (double)thr;
    for (unsigned q = tid; q < nib; q += 256) {
        unsigned key = ibl[q];
        int i = (int)(key >> 13), j = (int)(key & 8191u);
        const float4* a4 = reinterpret_cast<const float4*>(V + (size_t)i * DIM);
        const float4* b4 = reinterpret_cast<const float4*>(V + (size_t)j * DIM);
        double s = 0.0;
#pragma unroll 4
        for (int k = 0; k < DIM / 4; ++k) {
            float4 x = a4[k], y = b4[k];
            s += (double)x.x * y.x + (double)x.y * y.y
               + (double)x.z * y.z + (double)x.w * y.w;
        }
        if (s >= thrd) {
            unsigned p = atomicAdd(&ctr[0], 1u);
            if (p < CAP) edges[p] = key;
        }
    }
}

// ---------------------------------------------------------------------------
// fp32 fallback (exact path, no band) if ws is too small for Vh.
// ---------------------------------------------------------------------------
__global__ __launch_bounds__(256) void edge_kernel(
        const float* __restrict__ V,
        const float* __restrict__ thr_p,
        unsigned*    __restrict__ ctr,
        unsigned*    __restrict__ edges) {
    const int bi = blockIdx.y, bj = blockIdx.x;
    if (bj < bi) return;

    __shared__ float As[128 * 32];
    __shared__ float Bs[128 * 32];

    const float thr = thr_p[0];
    const int tid = threadIdx.x;
    const int tx = tid & 15, ty = tid >> 4;
    const int i0 = bi * 128, j0 = bj * 128;

    float acc[8][8];
#pragma unroll
    for (int r = 0; r < 8; ++r)
#pragma unroll
        for (int c = 0; c < 8; ++c) acc[r][c] = 0.f;

    const int srow = tid >> 3, sq = tid & 7;

    for (int kc = 0; kc < DIM; kc += 32) {
#pragma unroll
        for (int p = 0; p < 4; ++p) {
            int row = srow + 32 * p;
            float4 va = *reinterpret_cast<const float4*>(
                &V[(size_t)(i0 + row) * DIM + kc + sq * 4]);
            float4 vb = *reinterpret_cast<const float4*>(
                &V[(size_t)(j0 + row) * DIM + kc + sq * 4]);
            int w = row * 32 + ((sq ^ ((row >> 3) & 7)) << 2);
            *reinterpret_cast<float4*>(&As[w]) = va;
            *reinterpret_cast<float4*>(&Bs[w]) = vb;
        }
        __syncthreads();
#pragma unroll
        for (int k4 = 0; k4 < 8; ++k4) {
            const float* pA = &As[(ty * 8) * 32 + ((k4 ^ (ty & 7)) << 2)];
            const float* pB = &Bs[(tx * 8) * 32 + ((k4 ^ (tx & 7)) << 2)];
            float4 a[8], b[8];
#pragma unroll
            for (int r = 0; r < 8; ++r)
                a[r] = *reinterpret_cast<const float4*>(&pA[r * 32]);
#pragma unroll
            for (int c = 0; c < 8; ++c)
                b[c] = *reinterpret_cast<const float4*>(&pB[c * 32]);
#pragma unroll
            for (int r = 0; r < 8; ++r)
#pragma unroll
                for (int c = 0; c < 8; ++c) {
                    acc[r][c] = fmaf(a[r].x, b[c].x, acc[r][c]);
                    acc[r][c] = fmaf(a[r].y, b[c].y, acc[r][c]);
                    acc[r][c] = fmaf(a[r].z, b[c].z, acc[r][c]);
                    acc[r][c] = fmaf(a[r].w, b[c].w, acc[r][c]);
                }
        }
        __syncthreads();
    }
#pragma unroll
    for (int r = 0; r < 8; ++r)
#pragma unroll
        for (int c = 0; c < 8; ++c) {
            int i = i0 + ty * 8 + r;
            int j = j0 + tx * 8 + c;
            if (j > i && acc[r][c] >= thr) {
                unsigned p = atomicAdd(&ctr[0], 1u);
                if (p < CAP) edges[p] = ((unsigned)i << 13) | (unsigned)j;
            }
        }
}

// ---------------------------------------------------------------------------
// UF kernel (one block, 1024 threads): parallel winner-rounds exact replay
// of the sequential merge, then parallel root write-out.
//
// Winner-rounds correctness: per round each live edge e computes its current
// roots (ri,rj) and atomicMin's its packed key (= sequential order index)
// into S[ri], S[rj].  e applies iff it holds both slots.  (a) Every live
// edge f<e is then root-disjoint from e; disjoint unions commute, so e's
// state restricted to its roots equals its sequential state -> par[rj]=ri
// is the exact sequential effect.  (b) Winner root-sets are pairwise
// disjoint (shared root => equal slot value => equal key; keys unique), so
// parallel application + root-preserving compression is race-free, and
// concurrent phase-B finds cannot produce a false win: a re-found root r
// either carries S[r]==some other key (lose) or was bid by e itself.
// (c) The globally smallest live key always wins -> >=1 retire/round.
// Ping-pong slot arrays: phase B clears the OTHER array, so each round has
// exactly 2 barriers (the second fused into __syncthreads_count liveness).
// ---------------------------------------------------------------------------
__global__ __launch_bounds__(1024) void uf_kernel(
        const unsigned* __restrict__ ctr,
        const unsigned* __restrict__ edges,
        int* __restrict__ out) {
    __shared__ int      par[NPTS];        // 32 KB
    __shared__ unsigned slotA[NPTS];      // 32 KB
    __shared__ unsigned slotB[NPTS];      // 32 KB
    __shared__ unsigned sedge[LDSE];      // 32 KB

    const int tid = threadIdx.x;

    unsigned EC = ctr[0]; if (EC > LDSE) EC = LDSE;

    for (int t = tid; t < NPTS; t += 1024) {
        par[t] = t; slotA[t] = 0xFFFFFFFFu; slotB[t] = 0xFFFFFFFFu;
    }
    for (unsigned e = tid; e < EC; e += 1024) sedge[e] = edges[e];
    __syncthreads();

    volatile int* vpar = par;

    for (int round = 0;; ++round) {
        unsigned* S = (round & 1) ? slotB : slotA;
        unsigned* T = (round & 1) ? slotA : slotB;

        // Phase A: finds against round-start state + slot bids
        for (unsigned e = tid; e < EC; e += 1024) {
            unsigned key = sedge[e];
            if (key & 0x80000000u) continue;
            int ri = (int)(key >> 13), rj = (int)(key & 8191u);
            int p;
            while ((p = vpar[ri]) != ri) ri = p;
            while ((p = vpar[rj]) != rj) rj = p;
            atomicMin(&S[ri], key);
            atomicMin(&S[rj], key);
        }
        __syncthreads();

        // Phase B: winners apply; clear other slot array; track liveness
        int mylive = 0;
        for (unsigned e = tid; e < EC; e += 1024) {
            unsigned key = sedge[e];
            if (key & 0x80000000u) continue;
            int i = (int)(key >> 13), j = (int)(key & 8191u);
            int ri = i, rj = j, p;
            while ((p = vpar[ri]) != ri) ri = p;
            while ((p = vpar[rj]) != rj) rj = p;
            if (S[ri] == key && S[rj] == key) {
                if (ri != rj) { par[rj] = ri; par[i] = ri; par[j] = ri; }
                sedge[e] = key | 0x80000000u;
            } else {
                mylive = 1;
            }
        }
        for (int t = tid; t < NPTS; t += 1024) T[t] = 0xFFFFFFFFu;
        if (__syncthreads_count(mylive) == 0) break;
    }

    // ---- root write-out ----
    for (int t = tid; t < NPTS; t += 1024) {
        int r = t, p;
        while ((p = par[r]) != r) r = p;
        out[t] = r;
    }
}

extern "C" void kernel_launch(void* const* d_in, const int* in_sizes, int n_in,
                              void* d_out, int out_size, void* d_ws, size_t ws_size,
                              hipStream_t stream) {
    const float* V     = (const float*)d_in[0];
    const float* thr_p = (const float*)d_in[1];
    // d_in[2] (batch_size) provably does not affect the result.

    unsigned* ctr   = (unsigned*)d_ws;
    unsigned* edges = (unsigned*)((char*)d_ws + 64);
    int*      out   = (int*)d_out;

    const size_t vhOff = 1u << 20;
    const size_t vN    = (size_t)NPTS * DIM;
    const size_t need  = vhOff + vN * sizeof(_Float16) + 65536;

    if (ws_size >= need) {
        _Float16* Vh = (_Float16*)((char*)d_ws + vhOff);
        hipLaunchKernelGGL(convert_kernel, dim3(1024), dim3(256), 0, stream,
                           V, Vh, ctr);
        hipLaunchKernelGGL(edge_mfma, dim3(2080), dim3(256), 0, stream,
                           Vh, V, thr_p, ctr, edges);
    } else {
        hipLaunchKernelGGL(init_count, dim3(1), dim3(64), 0, stream, ctr);
        hipLaunchKernelGGL(edge_kernel, dim3(64, 64), dim3(256), 0, stream,
                           V, thr_p, ctr, edges);
    }
    hipLaunchKernelGGL(uf_kernel, dim3(1), dim3(1024), 0, stream,
                       ctr, edges, out);
}